// Round 12
// baseline (123.147 us; speedup 1.0000x reference)
//
#include <hip/hip_runtime.h>

#define B_ 16
#define F_ 128
#define N_ 256
#define T_ 64
#define C_ 64
#define ALPHA_ 0.2f
#define L2E_ 1.4426950408889634f

typedef short bf16x8 __attribute__((ext_vector_type(8)));
typedef float f32x4 __attribute__((ext_vector_type(4)));

__device__ __forceinline__ unsigned short f2bf(float x){
  unsigned int u = __float_as_uint(x);
  unsigned int r = u + 0x7FFFu + ((u >> 16) & 1u);   // RNE
  return (unsigned short)(r >> 16);
}
__device__ __forceinline__ unsigned pk2(float a, float b){
  return ((unsigned)f2bf(b) << 16) | (unsigned)f2bf(a);
}
// sign-extended single bit j of w: 0 -> 0x00000000, 1 -> 0xFFFFFFFF
__device__ __forceinline__ unsigned sbit(unsigned w, int j){
  return (unsigned)(((int)(w << (31 - j))) >> 31);
}
// LDS swizzle for Wh^T tile: varies with BOTH c&7 (read lanes) and c>>3 (write lanes)
__device__ __forceinline__ int swzT(int c){
  return ((c & 7) ^ ((c >> 3) & 7)) << 4;
}

// ---------------- Kernel B (fused): blocks [0,B*N): u (in-block, f32) + Wh via
// MFMA + f/g; blocks [B*N, B*N+B*4): adjacency bitmask build (independent)
__global__ __launch_bounds__(256, 4) void k_whm(const float* __restrict__ h,
    const float* __restrict__ W, const float* __restrict__ a,
    const int* __restrict__ adj,
    unsigned short* __restrict__ wht, float* __restrict__ fvec,
    float* __restrict__ gvec, unsigned* __restrict__ amask){
  __shared__ uint4 hT4[1024];    // 16KB: hT[t][f] bf16, 256B rows, XOR swz bits4-6
  __shared__ uint4 wT4[1024];    // 16KB: wT[c][f] bf16, same layout
  __shared__ float fpart[4][T_];
  __shared__ float gpart[4][T_];
  __shared__ float up[F_][2][2]; // 2KB: u partials [f][u1/u2][c-half]
  char* hT = (char*)hT4;
  char* wT = (char*)wT4;

  int bid = blockIdx.x;
  int tid = threadIdx.x, w = tid >> 6, l = tid & 63;

  if (bid >= B_*N_){
    // ---- mask half: adjacency row bitmasks, amask[b][n][8] u32
    int blk = bid - B_*N_;                // [0, B*4)
    int b = blk >> 2, r0 = (blk & 3)*64;
    const int* ab = adj + ((size_t)b*N_ + r0 + w*16)*N_;
    unsigned* om = amask + ((size_t)b*N_ + r0 + w*16)*8;
    for (int r = 0; r < 16; ++r){
      unsigned long long m0 = __ballot(ab[r*N_ +       l] > 0);
      unsigned long long m1 = __ballot(ab[r*N_ +  64 + l] > 0);
      unsigned long long m2 = __ballot(ab[r*N_ + 128 + l] > 0);
      unsigned long long m3 = __ballot(ab[r*N_ + 192 + l] > 0);
      if (l == 0){
        *(uint4*)(om + r*8)     = make_uint4((unsigned)m0, (unsigned)(m0>>32),
                                             (unsigned)m1, (unsigned)(m1>>32));
        *(uint4*)(om + r*8 + 4) = make_uint4((unsigned)m2, (unsigned)(m2>>32),
                                             (unsigned)m3, (unsigned)(m3>>32));
      }
    }
    return;
  }

  int b = bid >> 8, n = bid & 255;

  // ---- u partials (all-f32; W/a reads L2/L3-hot; 'a' wave-uniform -> scalar)
  {
    int f = tid & 127, chh = tid >> 7;         // chh wave-uniform
    const float* Wr  = W + (b*F_ + f)*C_ + chh*32;
    const float* ar1 = a + b*2*C_ + chh*32;
    const float* ar2 = ar1 + C_;
    float p1 = 0.f, p2 = 0.f;
#pragma unroll 8
    for (int c = 0; c < 32; ++c){
      float wv = Wr[c];
      p1 = fmaf(wv, ar1[c], p1);
      p2 = fmaf(wv, ar2[c], p2);
    }
    up[f][0][chh] = p1;
    up[f][1][chh] = p2;
  }
  __syncthreads();

  const float* hg = h + (size_t)b*F_*N_*T_ + n*T_;
  const float* Wg = W + b*F_*C_;

  float sf = 0.f, sg = 0.f;
#pragma unroll
  for (int p = 0; p < 4; ++p){
    int f0 = p*32 + w*8;
    float v[8], wv[8];
#pragma unroll
    for (int j = 0; j < 8; ++j){
      v[j]  = hg[(size_t)(f0+j)*(N_*T_) + l];      // coalesced 256B per wave
      wv[j] = Wg[(f0+j)*C_ + l];                   // coalesced 256B per wave
      float2 q1 = *(const float2*)&up[f0+j][0][0]; // uniform ds_read_b64
      float2 q2 = *(const float2*)&up[f0+j][1][0];
      sf = fmaf(v[j], q1.x + q1.y, sf);            // f32 f/g (precision-critical)
      sg = fmaf(v[j], q2.x + q2.y, sg);
    }
    uint4 ph = make_uint4(pk2(v[0],v[1]),  pk2(v[2],v[3]),  pk2(v[4],v[5]),  pk2(v[6],v[7]));
    uint4 pw = make_uint4(pk2(wv[0],wv[1]),pk2(wv[2],wv[3]),pk2(wv[4],wv[5]),pk2(wv[6],wv[7]));
    *(uint4*)(hT + ((l*256 + f0*2) ^ ((l & 7) << 4))) = ph;   // hT[t=l][f0..f0+7]
    *(uint4*)(wT + ((l*256 + f0*2) ^ ((l & 7) << 4))) = pw;   // wT[c=l][f0..f0+7]
  }
  fpart[w][l] = sf;
  gpart[w][l] = sg;
  __syncthreads();

  if (tid < T_){
    float f_ = (fpart[0][tid] + fpart[1][tid]) + (fpart[2][tid] + fpart[3][tid]);
    float g_ = (gpart[0][tid] + gpart[1][tid]) + (gpart[2][tid] + gpart[3][tid]);
    fvec[(b*N_ + n)*T_ + tid] = f_ * L2E_;     // coalesced 256B
    gvec[(b*N_ + n)*T_ + tid] = g_ * L2E_;
  }

  // MFMA: D[c][t], wave w owns c rows [w*16, w*16+16)
  int li = l & 15, g_ = l >> 4;
  bf16x8 afr[4];
#pragma unroll
  for (int ch = 0; ch < 4; ++ch){
    int c = w*16 + li;
    afr[ch] = *(bf16x8*)(wT + ((c*256 + (ch*32 + g_*8)*2) ^ ((c & 7) << 4)));
  }
  f32x4 acc[4];
#pragma unroll
  for (int tt = 0; tt < 4; ++tt) acc[tt] = (f32x4){0.f,0.f,0.f,0.f};
#pragma unroll
  for (int tt = 0; tt < 4; ++tt){
#pragma unroll
    for (int ch = 0; ch < 4; ++ch){
      int t = tt*16 + li;
      bf16x8 bfr = *(bf16x8*)(hT + ((t*256 + (ch*32 + g_*8)*2) ^ ((t & 7) << 4)));
      acc[tt] = __builtin_amdgcn_mfma_f32_16x16x32_bf16(afr[ch], bfr, acc[tt], 0, 0, 0);
    }
  }
  // store: lane holds t = tt*16+li (col), c = w*16 + g_*4 + reg (row)
  unsigned short* wb = wht + ((size_t)b*T_*N_ + n)*C_;
#pragma unroll
  for (int tt = 0; tt < 4; ++tt){
    int t = tt*16 + li;
    int c0 = w*16 + g_*4;
    unsigned q0 = pk2(acc[tt][0], acc[tt][1]);
    unsigned q1 = pk2(acc[tt][2], acc[tt][3]);
    *(uint2*)(wb + (size_t)t*(N_*C_) + c0) = make_uint2(q0, q1);
  }
}

// ---------------- Kernel C: per (b,t), 256 threads (R10 structure): T14 async-
// stage, masked-row-max softmax (tree-max), MFMA PV (ch-unroll-2), direct bf16
// epilogue into own wht slab (t,n,c)
__global__ __launch_bounds__(256, 4) void k_attn(
    unsigned short* wht,                      // [b][t][n][c] bf16 (in AND out)
    const unsigned* __restrict__ amask,       // [b][n][8]
    const float* __restrict__ fvec,           // [b][n][t], pre-scaled by log2e
    const float* __restrict__ gvec){          // [b][n][t], pre-scaled by log2e
  __shared__ uint4 whsT4[2048];   // 32KB: Wh^T [c][m] bf16, swzT-swizzled
  __shared__ float gs[N_];
  __shared__ float fs[N_];
  __shared__ float invs[N_];
  char* dstT = (char*)whsT4;

  int bid = blockIdx.x;
  int b = bid >> 6, t = bid & 63;
  int tid = threadIdx.x, w = tid >> 6, l = tid & 63;
  int li = l & 15, g_ = l >> 4;

  // (1) f/g rows -> LDS (4B stride-T reads, L2-hot across the 64 t-blocks of b)
  gs[tid] = gvec[(b*N_ + tid)*T_ + t];
  fs[tid] = fvec[(b*N_ + tid)*T_ + t];

  // (2) masks (2 x uint4 per row) -> packed pkl/pkh (mt-unrolled regs, no scratch)
  uint4 mlo[4], mhi[4];
#pragma unroll
  for (int mt = 0; mt < 4; ++mt){
    int n = w*64 + mt*16 + li;
    const uint4* mp = (const uint4*)(amask + ((size_t)b*N_ + n)*8);
    mlo[mt] = mp[0];
    mhi[mt] = mp[1];
  }
  unsigned pkl[4], pkh[4];
  unsigned selA = 0x0C0C0000u | ((unsigned)(g_ + 4) << 8) | (unsigned)g_;
#pragma unroll
  for (int mt = 0; mt < 4; ++mt){
    unsigned t0 = __builtin_amdgcn_perm(mlo[mt].y, mlo[mt].x, selA);
    unsigned t1 = __builtin_amdgcn_perm(mlo[mt].w, mlo[mt].z, selA);
    pkl[mt] = __builtin_amdgcn_perm(t1, t0, 0x05040100u);
    unsigned t2 = __builtin_amdgcn_perm(mhi[mt].y, mhi[mt].x, selA);
    unsigned t3 = __builtin_amdgcn_perm(mhi[mt].w, mhi[mt].z, selA);
    pkh[mt] = __builtin_amdgcn_perm(t3, t2, 0x05040100u);
  }

  // (3) ISSUE Wh staged loads (drain deferred past pass 1 — T14 split)
  const char* src = (const char*)(wht + (size_t)(b*T_ + t)*(N_*C_));
  uint4 ra[4], rb[4];
#pragma unroll
  for (int i = 0; i < 4; ++i){
    int q2 = tid + i*256;                  // 1024 2-row x 8-col tiles
    int m = (q2 >> 3)*2, c0 = (q2 & 7)*8;
    ra[i] = *(const uint4*)(src + m*128 + c0*2);
    rb[i] = *(const uint4*)(src + (m+1)*128 + c0*2);
  }

  // (4) barrier #1: LDS-only drain (raw s_barrier; staged loads stay in flight —
  // __syncthreads would emit vmcnt(0) and kill the overlap)
  asm volatile("s_waitcnt lgkmcnt(0)" ::: "memory");
  __builtin_amdgcn_sched_barrier(0);
  __builtin_amdgcn_s_barrier();

  float fl2[4];
#pragma unroll
  for (int mt = 0; mt < 4; ++mt) fl2[mt] = fs[w*64 + mt*16 + li];

  // (5) pass 1 (overlaps in-flight staged loads): masked per-row max of g.
  // Masked -> +0.0 (exact w.o.p.). Must be the TRUE masked max (R5 NaN lesson).
  // Tree-shaped for v_max3 fusion (T17).
  float mg[4] = {0.f, 0.f, 0.f, 0.f};
#pragma unroll 1
  for (int ch = 0; ch < 8; ++ch){
    const float* gq = &gs[ch*32 + g_*8];
    float4 ga = *(const float4*)gq;
    float4 gb = *(const float4*)(gq + 4);
    float gg[8] = {ga.x, ga.y, ga.z, ga.w, gb.x, gb.y, gb.z, gb.w};
    int sh = (ch & 3)*8;                    // wave-uniform -> SGPR
#pragma unroll
    for (int mt = 0; mt < 4; ++mt){
      unsigned wsh = ((ch & 4) ? pkh[mt] : pkl[mt]) >> sh;   // s_cselect + shift
      float cd[8];
#pragma unroll
      for (int j = 0; j < 8; ++j)
        cd[j] = __uint_as_float(__float_as_uint(gg[j]) & sbit(wsh, j));
      float m01 = fmaxf(cd[0], cd[1]), m23 = fmaxf(cd[2], cd[3]);
      float m45 = fmaxf(cd[4], cd[5]), m67 = fmaxf(cd[6], cd[7]);
      mg[mt] = fmaxf(mg[mt], fmaxf(fmaxf(m01, m23), fmaxf(m45, m67)));
    }
  }
  float fme[4], fme2[4];
#pragma unroll
  for (int mt = 0; mt < 4; ++mt){
    float v = mg[mt];
    v = fmaxf(v, __shfl_xor(v, 16));
    v = fmaxf(v, __shfl_xor(v, 32));
    float em = fl2[mt] + v;
    float M  = fmaxf(em, ALPHA_*em);     // exact masked row max of lrelu-logit (x L2E)
    fme[mt]  = fl2[mt] - M;
    fme2[mt] = fmaf(fl2[mt], ALPHA_, -M);
  }

  // (6) drain staged loads (counted vmcnt, compiler-inserted) -> perm -> LDS
#pragma unroll
  for (int i = 0; i < 4; ++i){
    int q2 = tid + i*256;
    int m = (q2 >> 3)*2, c0 = (q2 & 7)*8;
    unsigned va[4] = {ra[i].x, ra[i].y, ra[i].z, ra[i].w};
    unsigned vb[4] = {rb[i].x, rb[i].y, rb[i].z, rb[i].w};
#pragma unroll
    for (int k = 0; k < 4; ++k){
      int c = c0 + 2*k;
      unsigned lo = __builtin_amdgcn_perm(vb[k], va[k], 0x05040100u); // (m+1|m) @ col c
      unsigned hi = __builtin_amdgcn_perm(vb[k], va[k], 0x07060302u); // (m+1|m) @ col c+1
      *(unsigned*)(dstT + ((c*512 + m*2)     ^ swzT(c)))   = lo;
      *(unsigned*)(dstT + (((c+1)*512 + m*2) ^ swzT(c+1))) = hi;
    }
  }
  __syncthreads();

  // (7) pass 2: weights in A-frag layout -> MFMA PV (unroll 2: next-ch ds_reads
  // issue under current-ch exp/cvt/MFMA chain)
  f32x4 acc[4][4];
#pragma unroll
  for (int mt = 0; mt < 4; ++mt)
#pragma unroll
    for (int nt = 0; nt < 4; ++nt)
      acc[mt][nt] = (f32x4){0.f, 0.f, 0.f, 0.f};
  float s0[4] = {0.f,0.f,0.f,0.f}, s1[4] = {0.f,0.f,0.f,0.f};

#pragma unroll 2
  for (int ch = 0; ch < 8; ++ch){
    bf16x8 bfr[4];
#pragma unroll
    for (int nt = 0; nt < 4; ++nt){
      int c = nt*16 + li;
      bfr[nt] = *(bf16x8*)(dstT + ((c*512 + (ch*32 + g_*8)*2) ^ swzT(c)));
    }
    const float* gq = &gs[ch*32 + g_*8];
    float4 ga = *(const float4*)gq;
    float4 gb = *(const float4*)(gq + 4);
    float gg[8] = {ga.x, ga.y, ga.z, ga.w, gb.x, gb.y, gb.z, gb.w};
    int sh = (ch & 3)*8;
#pragma unroll
    for (int mt = 0; mt < 4; ++mt){
      unsigned wsh = ((ch & 4) ? pkh[mt] : pkl[mt]) >> sh;
      float wv[8];
#pragma unroll
      for (int j = 0; j < 8; ++j){
        float d1 = gg[j] + fme[mt];                    // (lr - M)*L2E, branch 1
        float d2 = fmaf(gg[j], ALPHA_, fme2[mt]);      // branch 2
        float p  = exp2f(fmaxf(d1, d2));               // v_exp_f32
        float v  = __uint_as_float(__float_as_uint(p) & sbit(wsh, j));
        if (j < 4) s0[mt] += v; else s1[mt] += v;      // dual chains for ILP
        wv[j] = v;
      }
      unsigned q0, q1, q2_, q3;
      asm("v_cvt_pk_bf16_f32 %0, %1, %2" : "=v"(q0)  : "v"(wv[0]), "v"(wv[1]));
      asm("v_cvt_pk_bf16_f32 %0, %1, %2" : "=v"(q1)  : "v"(wv[2]), "v"(wv[3]));
      asm("v_cvt_pk_bf16_f32 %0, %1, %2" : "=v"(q2_) : "v"(wv[4]), "v"(wv[5]));
      asm("v_cvt_pk_bf16_f32 %0, %1, %2" : "=v"(q3)  : "v"(wv[6]), "v"(wv[7]));
      union { unsigned u[4]; bf16x8 v; } afu;
      afu.u[0] = q0; afu.u[1] = q1; afu.u[2] = q2_; afu.u[3] = q3;
#pragma unroll
      for (int nt = 0; nt < 4; ++nt)
        acc[mt][nt] = __builtin_amdgcn_mfma_f32_16x16x32_bf16(afu.v, bfr[nt], acc[mt][nt], 0, 0, 0);
    }
  }

  // ---- row sums -> invs (wave-local; same-wave ds_write/ds_read, no barrier)
#pragma unroll
  for (int mt = 0; mt < 4; ++mt){
    float s = s0[mt] + s1[mt];
    s += __shfl_xor(s, 16);
    s += __shfl_xor(s, 32);
    if (g_ == 0) invs[w*64 + mt*16 + li] = 1.0f / s;
  }

  // ---- epilogue: normalize + elu -> bf16 -> DIRECT global stores into own slab
  unsigned short* ob = wht + (size_t)(b*T_ + t)*(N_*C_);
#pragma unroll
  for (int mt = 0; mt < 4; ++mt){
#pragma unroll
    for (int reg = 0; reg < 4; ++reg){
      int nloc = w*64 + mt*16 + g_*4 + reg;     // D layout: row = g_*4+reg
      float inv = invs[nloc];
#pragma unroll
      for (int nt = 0; nt < 4; ++nt){
        float v = acc[mt][nt][reg] * inv;
        v = v > 0.f ? v : (__expf(v) - 1.f);    // elu
        ob[nloc*C_ + nt*16 + li] = f2bf(v);
      }
    }
  }
}

// ---------------- Kernel D: (b,t,n,c) bf16 -> (b,c,n,t) f32
__global__ __launch_bounds__(256) void k_tr(const unsigned short* __restrict__ whtO,
                                            float* __restrict__ out){
  __shared__ float tile[64][65];
  int bid = blockIdx.x;
  int b = bid >> 8, n = bid & 255;
  int tid = threadIdx.x;
  const unsigned short* src = whtO + ((size_t)b*T_*N_ + n)*C_;   // + t*N*C + c
#pragma unroll
  for (int i = 0; i < 2; ++i){
    int idx = tid + i*256;                 // 512 uint4 chunks: 64 t-rows x 8
    int t = idx >> 3, c0 = (idx & 7)*8;
    uint4 v = *(const uint4*)(src + (size_t)t*(N_*C_) + c0);
    unsigned arr[4] = {v.x, v.y, v.z, v.w};
#pragma unroll
    for (int k = 0; k < 4; ++k){
      tile[c0+2*k  ][t] = __uint_as_float(arr[k] << 16);
      tile[c0+2*k+1][t] = __uint_as_float(arr[k] & 0xFFFF0000u);
    }
  }
  __syncthreads();
  float* ob = out + (size_t)b*C_*N_*T_ + n*T_;                   // + c*N*T + t
#pragma unroll
  for (int i = 0; i < 4; ++i){
    int idx = tid + i*256;                 // 1024 float4: 64 c-rows x 16
    int c = idx >> 4, t0 = (idx & 15)*4;
    float4 v = make_float4(tile[c][t0], tile[c][t0+1], tile[c][t0+2], tile[c][t0+3]);
    *(float4*)(ob + (size_t)c*(N_*T_) + t0) = v;
  }
}

extern "C" void kernel_launch(void* const* d_in, const int* in_sizes, int n_in,
                              void* d_out, int out_size, void* d_ws, size_t ws_size,
                              hipStream_t stream){
  (void)in_sizes; (void)n_in; (void)out_size; (void)ws_size;
  const float* h   = (const float*)d_in[0];
  const int*   adj = (const int*)d_in[1];
  const float* W   = (const float*)d_in[2];
  const float* a   = (const float*)d_in[3];
  float* u    = (float*)d_ws;                       // (unused; layout kept)
  float* fvec = u + 2*B_*F_;                        // B*N*T f32 (scaled, [b][n][t])
  float* gvec = fvec + B_*N_*T_;                    // B*N*T f32 (scaled, [b][n][t])
  unsigned short* wht = (unsigned short*)(gvec + B_*N_*T_);  // B*T*N*C bf16
  unsigned* amask = (unsigned*)(wht + (size_t)B_*T_*N_*C_);  // B*N*8 u32

  k_whm <<<dim3(B_*N_ + B_*4), dim3(256), 0, stream>>>(h, W, a, adj, wht, fvec, gvec, amask);
  k_attn<<<dim3(B_*T_),        dim3(256), 0, stream>>>(wht, amask, fvec, gvec);
  k_tr  <<<dim3(B_*N_),        dim3(256), 0, stream>>>(wht, (float*)d_out);
}

// Round 13
// 105.492 us; speedup vs baseline: 1.1674x; 1.1674x over previous
//
#include <hip/hip_runtime.h>

#define B_ 16
#define F_ 128
#define N_ 256
#define T_ 64
#define C_ 64
#define ALPHA_ 0.2f
#define L2E_ 1.4426950408889634f

typedef short bf16x8 __attribute__((ext_vector_type(8)));
typedef float f32x4 __attribute__((ext_vector_type(4)));

__device__ __forceinline__ unsigned short f2bf(float x){
  unsigned int u = __float_as_uint(x);
  unsigned int r = u + 0x7FFFu + ((u >> 16) & 1u);   // RNE
  return (unsigned short)(r >> 16);
}
__device__ __forceinline__ unsigned pk2(float a, float b){
  return ((unsigned)f2bf(b) << 16) | (unsigned)f2bf(a);
}
// sign-extended single bit j of w: 0 -> 0x00000000, 1 -> 0xFFFFFFFF
__device__ __forceinline__ unsigned sbit(unsigned w, int j){
  return (unsigned)(((int)(w << (31 - j))) >> 31);
}
// LDS swizzle for Wh^T tile: varies with BOTH c&7 (read lanes) and c>>3 (write lanes)
__device__ __forceinline__ int swzT(int c){
  return ((c & 7) ^ ((c >> 3) & 7)) << 4;
}

// ---------------- Kernel A: u1[b][f] = sum_c W[b][f][c]*a1[b][c]; u2 with a2
__global__ void k_u(const float* __restrict__ W, const float* __restrict__ a,
                    float* __restrict__ u){
  int b = blockIdx.x, f = threadIdx.x;            // grid(B), block(F)
  const float* Wb = W + (b*F_ + f)*C_;
  const float* ab = a + b*2*C_;
  float s1 = 0.f, s2 = 0.f;
#pragma unroll 8
  for (int c = 0; c < C_; ++c){
    float w = Wb[c];
    s1 = fmaf(w, ab[c], s1);
    s2 = fmaf(w, ab[C_ + c], s2);
  }
  u[b*F_ + f] = s1;
  u[B_*F_ + b*F_ + f] = s2;
}

// ---------------- Kernel B (fused): blocks [0,B*N): Wh via MFMA + f/g;
// blocks [B*N, B*N + B*4): adjacency bitmask build (no data dep between halves)
__global__ __launch_bounds__(256, 4) void k_whm(const float* __restrict__ h,
    const float* __restrict__ W, const float* __restrict__ u,
    const int* __restrict__ adj,
    unsigned short* __restrict__ wht, float* __restrict__ fvec,
    float* __restrict__ gvec, unsigned* __restrict__ amask){
  __shared__ uint4 hT4[1024];    // 16KB: hT[t][f] bf16, 256B rows, XOR swz bits4-6
  __shared__ uint4 wT4[1024];    // 16KB: wT[c][f] bf16, same layout
  __shared__ float fpart[4][T_];
  __shared__ float gpart[4][T_];
  char* hT = (char*)hT4;
  char* wT = (char*)wT4;

  int bid = blockIdx.x;
  int tid = threadIdx.x, w = tid >> 6, l = tid & 63;

  if (bid >= B_*N_){
    // ---- mask half: adjacency row bitmasks, amask[b][n][8] u32
    int blk = bid - B_*N_;                // [0, B*4)
    int b = blk >> 2, r0 = (blk & 3)*64;
    const int* ab = adj + ((size_t)b*N_ + r0 + w*16)*N_;
    unsigned* om = amask + ((size_t)b*N_ + r0 + w*16)*8;
    for (int r = 0; r < 16; ++r){
      unsigned long long m0 = __ballot(ab[r*N_ +       l] > 0);
      unsigned long long m1 = __ballot(ab[r*N_ +  64 + l] > 0);
      unsigned long long m2 = __ballot(ab[r*N_ + 128 + l] > 0);
      unsigned long long m3 = __ballot(ab[r*N_ + 192 + l] > 0);
      if (l == 0){
        *(uint4*)(om + r*8)     = make_uint4((unsigned)m0, (unsigned)(m0>>32),
                                             (unsigned)m1, (unsigned)(m1>>32));
        *(uint4*)(om + r*8 + 4) = make_uint4((unsigned)m2, (unsigned)(m2>>32),
                                             (unsigned)m3, (unsigned)(m3>>32));
      }
    }
    return;
  }

  int b = bid >> 8, n = bid & 255;
  const float* hg = h + (size_t)b*F_*N_*T_ + n*T_;
  const float* Wg = W + b*F_*C_;
  const float* u1 = u + b*F_;
  const float* u2 = u + B_*F_ + b*F_;

  float sf = 0.f, sg = 0.f;
#pragma unroll
  for (int p = 0; p < 4; ++p){
    int f0 = p*32 + w*8;
    float v[8], wv[8];
#pragma unroll
    for (int j = 0; j < 8; ++j){
      v[j]  = hg[(size_t)(f0+j)*(N_*T_) + l];      // coalesced 256B per wave
      wv[j] = Wg[(f0+j)*C_ + l];                   // coalesced 256B per wave
      sf = fmaf(v[j], u1[f0+j], sf);               // f32 f/g (precision-critical)
      sg = fmaf(v[j], u2[f0+j], sg);
    }
    uint4 ph = make_uint4(pk2(v[0],v[1]),  pk2(v[2],v[3]),  pk2(v[4],v[5]),  pk2(v[6],v[7]));
    uint4 pw = make_uint4(pk2(wv[0],wv[1]),pk2(wv[2],wv[3]),pk2(wv[4],wv[5]),pk2(wv[6],wv[7]));
    *(uint4*)(hT + ((l*256 + f0*2) ^ ((l & 7) << 4))) = ph;   // hT[t=l][f0..f0+7]
    *(uint4*)(wT + ((l*256 + f0*2) ^ ((l & 7) << 4))) = pw;   // wT[c=l][f0..f0+7]
  }
  fpart[w][l] = sf;
  gpart[w][l] = sg;
  __syncthreads();

  if (tid < T_){
    float f_ = (fpart[0][tid] + fpart[1][tid]) + (fpart[2][tid] + fpart[3][tid]);
    float g_ = (gpart[0][tid] + gpart[1][tid]) + (gpart[2][tid] + gpart[3][tid]);
    fvec[(b*N_ + n)*T_ + tid] = f_ * L2E_;     // coalesced 256B
    gvec[(b*N_ + n)*T_ + tid] = g_ * L2E_;
  }

  // MFMA: D[c][t], wave w owns c rows [w*16, w*16+16)
  int li = l & 15, g_ = l >> 4;
  bf16x8 afr[4];
#pragma unroll
  for (int ch = 0; ch < 4; ++ch){
    int c = w*16 + li;
    afr[ch] = *(bf16x8*)(wT + ((c*256 + (ch*32 + g_*8)*2) ^ ((c & 7) << 4)));
  }
  f32x4 acc[4];
#pragma unroll
  for (int tt = 0; tt < 4; ++tt) acc[tt] = (f32x4){0.f,0.f,0.f,0.f};
#pragma unroll
  for (int tt = 0; tt < 4; ++tt){
#pragma unroll
    for (int ch = 0; ch < 4; ++ch){
      int t = tt*16 + li;
      bf16x8 bfr = *(bf16x8*)(hT + ((t*256 + (ch*32 + g_*8)*2) ^ ((t & 7) << 4)));
      acc[tt] = __builtin_amdgcn_mfma_f32_16x16x32_bf16(afr[ch], bfr, acc[tt], 0, 0, 0);
    }
  }

  // ---- LDS-bounce store: partial 8B/t-strided scatter -> full-line writes.
  // (Old path: each 128B (t,n) line of wht got 16 separate 8B writes from 4
  // different waves -> up to 16x write transactions.)
  __syncthreads();                       // all waves done reading hT/wT
  char* outT = hT;                       // reuse 8KB: outT[t][c] bf16, slot^=(t&7)
#pragma unroll
  for (int tt = 0; tt < 4; ++tt){
    int t = tt*16 + li;
    int c0 = w*16 + g_*4;
    unsigned q0 = pk2(acc[tt][0], acc[tt][1]);
    unsigned q1 = pk2(acc[tt][2], acc[tt][3]);
    *(uint2*)(outT + ((t*128 + c0*2) ^ ((t & 7) << 4))) = make_uint2(q0, q1);
  }
  __syncthreads();
  unsigned short* wb = wht + (size_t)b*T_*N_*C_ + n*C_;
#pragma unroll
  for (int k = 0; k < 2; ++k){
    int idx = tid + k*256;               // 512 16B chunks: 64 t x 8 c-slots
    int t = idx >> 3, c8 = idx & 7;
    uint4 vq = *(const uint4*)(outT + t*128 + ((c8 ^ (t & 7)) << 4));
    *(uint4*)(wb + (size_t)t*(N_*C_) + c8*8) = vq;   // full 128B line per t
  }
}

// ---------------- Kernel C: per (b,t), 256 threads: T14 async-stage, masked-
// row-max softmax (tree-max), MFMA PV (ch-unroll-2), direct bf16 epilogue
// into own wht slab (t,n,c)
__global__ __launch_bounds__(256, 4) void k_attn(
    unsigned short* wht,                      // [b][t][n][c] bf16 (in AND out)
    const unsigned* __restrict__ amask,       // [b][n][8]
    const float* __restrict__ fvec,           // [b][n][t], pre-scaled by log2e
    const float* __restrict__ gvec){          // [b][n][t], pre-scaled by log2e
  __shared__ uint4 whsT4[2048];   // 32KB: Wh^T [c][m] bf16, swzT-swizzled
  __shared__ float gs[N_];
  __shared__ float fs[N_];
  __shared__ float invs[N_];
  char* dstT = (char*)whsT4;

  int bid = blockIdx.x;
  int b = bid >> 6, t = bid & 63;
  int tid = threadIdx.x, w = tid >> 6, l = tid & 63;
  int li = l & 15, g_ = l >> 4;

  // (1) f/g rows -> LDS (4B stride-T reads, L2-hot across the 64 t-blocks of b)
  gs[tid] = gvec[(b*N_ + tid)*T_ + t];
  fs[tid] = fvec[(b*N_ + tid)*T_ + t];

  // (2) masks (2 x uint4 per row) -> packed pkl/pkh (mt-unrolled regs, no scratch)
  uint4 mlo[4], mhi[4];
#pragma unroll
  for (int mt = 0; mt < 4; ++mt){
    int n = w*64 + mt*16 + li;
    const uint4* mp = (const uint4*)(amask + ((size_t)b*N_ + n)*8);
    mlo[mt] = mp[0];
    mhi[mt] = mp[1];
  }
  unsigned pkl[4], pkh[4];
  unsigned selA = 0x0C0C0000u | ((unsigned)(g_ + 4) << 8) | (unsigned)g_;
#pragma unroll
  for (int mt = 0; mt < 4; ++mt){
    unsigned t0 = __builtin_amdgcn_perm(mlo[mt].y, mlo[mt].x, selA);
    unsigned t1 = __builtin_amdgcn_perm(mlo[mt].w, mlo[mt].z, selA);
    pkl[mt] = __builtin_amdgcn_perm(t1, t0, 0x05040100u);
    unsigned t2 = __builtin_amdgcn_perm(mhi[mt].y, mhi[mt].x, selA);
    unsigned t3 = __builtin_amdgcn_perm(mhi[mt].w, mhi[mt].z, selA);
    pkh[mt] = __builtin_amdgcn_perm(t3, t2, 0x05040100u);
  }

  // (3) ISSUE Wh staged loads (drain deferred past pass 1 — T14 split)
  const char* src = (const char*)(wht + (size_t)(b*T_ + t)*(N_*C_));
  uint4 ra[4], rb[4];
#pragma unroll
  for (int i = 0; i < 4; ++i){
    int q2 = tid + i*256;                  // 1024 2-row x 8-col tiles
    int m = (q2 >> 3)*2, c0 = (q2 & 7)*8;
    ra[i] = *(const uint4*)(src + m*128 + c0*2);
    rb[i] = *(const uint4*)(src + (m+1)*128 + c0*2);
  }

  // (4) barrier #1: LDS-only drain (raw s_barrier; staged loads stay in flight —
  // __syncthreads would emit vmcnt(0) and kill the overlap)
  asm volatile("s_waitcnt lgkmcnt(0)" ::: "memory");
  __builtin_amdgcn_sched_barrier(0);
  __builtin_amdgcn_s_barrier();

  float fl2[4];
#pragma unroll
  for (int mt = 0; mt < 4; ++mt) fl2[mt] = fs[w*64 + mt*16 + li];

  // (5) pass 1 (overlaps in-flight staged loads): masked per-row max of g.
  // Masked -> +0.0 (exact w.o.p.). Must be the TRUE masked max (R5 NaN lesson).
  // Tree-shaped for v_max3 fusion (T17).
  float mg[4] = {0.f, 0.f, 0.f, 0.f};
#pragma unroll 1
  for (int ch = 0; ch < 8; ++ch){
    const float* gq = &gs[ch*32 + g_*8];
    float4 ga = *(const float4*)gq;
    float4 gb = *(const float4*)(gq + 4);
    float gg[8] = {ga.x, ga.y, ga.z, ga.w, gb.x, gb.y, gb.z, gb.w};
    int sh = (ch & 3)*8;                    // wave-uniform -> SGPR
#pragma unroll
    for (int mt = 0; mt < 4; ++mt){
      unsigned wsh = ((ch & 4) ? pkh[mt] : pkl[mt]) >> sh;   // s_cselect + shift
      float cd[8];
#pragma unroll
      for (int j = 0; j < 8; ++j)
        cd[j] = __uint_as_float(__float_as_uint(gg[j]) & sbit(wsh, j));
      float m01 = fmaxf(cd[0], cd[1]), m23 = fmaxf(cd[2], cd[3]);
      float m45 = fmaxf(cd[4], cd[5]), m67 = fmaxf(cd[6], cd[7]);
      mg[mt] = fmaxf(mg[mt], fmaxf(fmaxf(m01, m23), fmaxf(m45, m67)));
    }
  }
  float fme[4], fme2[4];
#pragma unroll
  for (int mt = 0; mt < 4; ++mt){
    float v = mg[mt];
    v = fmaxf(v, __shfl_xor(v, 16));
    v = fmaxf(v, __shfl_xor(v, 32));
    float em = fl2[mt] + v;
    float M  = fmaxf(em, ALPHA_*em);     // exact masked row max of lrelu-logit (x L2E)
    fme[mt]  = fl2[mt] - M;
    fme2[mt] = fmaf(fl2[mt], ALPHA_, -M);
  }

  // (6) drain staged loads (counted vmcnt, compiler-inserted) -> perm -> LDS
#pragma unroll
  for (int i = 0; i < 4; ++i){
    int q2 = tid + i*256;
    int m = (q2 >> 3)*2, c0 = (q2 & 7)*8;
    unsigned va[4] = {ra[i].x, ra[i].y, ra[i].z, ra[i].w};
    unsigned vb[4] = {rb[i].x, rb[i].y, rb[i].z, rb[i].w};
#pragma unroll
    for (int k = 0; k < 4; ++k){
      int c = c0 + 2*k;
      unsigned lo = __builtin_amdgcn_perm(vb[k], va[k], 0x05040100u); // (m+1|m) @ col c
      unsigned hi = __builtin_amdgcn_perm(vb[k], va[k], 0x07060302u); // (m+1|m) @ col c+1
      *(unsigned*)(dstT + ((c*512 + m*2)     ^ swzT(c)))   = lo;
      *(unsigned*)(dstT + (((c+1)*512 + m*2) ^ swzT(c+1))) = hi;
    }
  }
  __syncthreads();

  // (7) pass 2: weights in A-frag layout -> MFMA PV (unroll 2: next-ch ds_reads
  // issue under current-ch exp/cvt/MFMA chain)
  f32x4 acc[4][4];
#pragma unroll
  for (int mt = 0; mt < 4; ++mt)
#pragma unroll
    for (int nt = 0; nt < 4; ++nt)
      acc[mt][nt] = (f32x4){0.f, 0.f, 0.f, 0.f};
  float s0[4] = {0.f,0.f,0.f,0.f}, s1[4] = {0.f,0.f,0.f,0.f};

#pragma unroll 2
  for (int ch = 0; ch < 8; ++ch){
    bf16x8 bfr[4];
#pragma unroll
    for (int nt = 0; nt < 4; ++nt){
      int c = nt*16 + li;
      bfr[nt] = *(bf16x8*)(dstT + ((c*512 + (ch*32 + g_*8)*2) ^ swzT(c)));
    }
    const float* gq = &gs[ch*32 + g_*8];
    float4 ga = *(const float4*)gq;
    float4 gb = *(const float4*)(gq + 4);
    float gg[8] = {ga.x, ga.y, ga.z, ga.w, gb.x, gb.y, gb.z, gb.w};
    int sh = (ch & 3)*8;
#pragma unroll
    for (int mt = 0; mt < 4; ++mt){
      unsigned wsh = ((ch & 4) ? pkh[mt] : pkl[mt]) >> sh;
      float wv[8];
#pragma unroll
      for (int j = 0; j < 8; ++j){
        float d1 = gg[j] + fme[mt];                    // (lr - M)*L2E, branch 1
        float d2 = fmaf(gg[j], ALPHA_, fme2[mt]);      // branch 2
        float p  = exp2f(fmaxf(d1, d2));               // v_exp_f32
        float v  = __uint_as_float(__float_as_uint(p) & sbit(wsh, j));
        if (j < 4) s0[mt] += v; else s1[mt] += v;      // dual chains for ILP
        wv[j] = v;
      }
      unsigned q0, q1, q2_, q3;
      asm("v_cvt_pk_bf16_f32 %0, %1, %2" : "=v"(q0)  : "v"(wv[0]), "v"(wv[1]));
      asm("v_cvt_pk_bf16_f32 %0, %1, %2" : "=v"(q1)  : "v"(wv[2]), "v"(wv[3]));
      asm("v_cvt_pk_bf16_f32 %0, %1, %2" : "=v"(q2_) : "v"(wv[4]), "v"(wv[5]));
      asm("v_cvt_pk_bf16_f32 %0, %1, %2" : "=v"(q3)  : "v"(wv[6]), "v"(wv[7]));
      union { unsigned u[4]; bf16x8 v; } afu;
      afu.u[0] = q0; afu.u[1] = q1; afu.u[2] = q2_; afu.u[3] = q3;
#pragma unroll
      for (int nt = 0; nt < 4; ++nt)
        acc[mt][nt] = __builtin_amdgcn_mfma_f32_16x16x32_bf16(afu.v, bfr[nt], acc[mt][nt], 0, 0, 0);
    }
  }

  // ---- row sums -> invs (wave-local; same-wave ds_write/ds_read, no barrier)
#pragma unroll
  for (int mt = 0; mt < 4; ++mt){
    float s = s0[mt] + s1[mt];
    s += __shfl_xor(s, 16);
    s += __shfl_xor(s, 32);
    if (g_ == 0) invs[w*64 + mt*16 + li] = 1.0f / s;
  }

  // ---- epilogue: normalize + elu -> bf16 -> DIRECT global stores into own slab
  // (32B pieces per instruction from one wave -> L2 write-combines; R9 vs R10
  // showed this beats an LDS bounce here)
  unsigned short* ob = wht + (size_t)(b*T_ + t)*(N_*C_);
#pragma unroll
  for (int mt = 0; mt < 4; ++mt){
#pragma unroll
    for (int reg = 0; reg < 4; ++reg){
      int nloc = w*64 + mt*16 + g_*4 + reg;     // D layout: row = g_*4+reg
      float inv = invs[nloc];
#pragma unroll
      for (int nt = 0; nt < 4; ++nt){
        float v = acc[mt][nt][reg] * inv;
        v = v > 0.f ? v : (__expf(v) - 1.f);    // elu
        ob[nloc*C_ + nt*16 + li] = f2bf(v);
      }
    }
  }
}

// ---------------- Kernel D: (b,t,n,c) bf16 -> (b,c,n,t) f32
__global__ __launch_bounds__(256) void k_tr(const unsigned short* __restrict__ whtO,
                                            float* __restrict__ out){
  __shared__ float tile[64][65];
  int bid = blockIdx.x;
  int b = bid >> 8, n = bid & 255;
  int tid = threadIdx.x;
  const unsigned short* src = whtO + ((size_t)b*T_*N_ + n)*C_;   // + t*N*C + c
#pragma unroll
  for (int i = 0; i < 2; ++i){
    int idx = tid + i*256;                 // 512 uint4 chunks: 64 t-rows x 8
    int t = idx >> 3, c0 = (idx & 7)*8;
    uint4 v = *(const uint4*)(src + (size_t)t*(N_*C_) + c0);
    unsigned arr[4] = {v.x, v.y, v.z, v.w};
#pragma unroll
    for (int k = 0; k < 4; ++k){
      tile[c0+2*k  ][t] = __uint_as_float(arr[k] << 16);
      tile[c0+2*k+1][t] = __uint_as_float(arr[k] & 0xFFFF0000u);
    }
  }
  __syncthreads();
  float* ob = out + (size_t)b*C_*N_*T_ + n*T_;                   // + c*N*T + t
#pragma unroll
  for (int i = 0; i < 4; ++i){
    int idx = tid + i*256;                 // 1024 float4: 64 c-rows x 16
    int c = idx >> 4, t0 = (idx & 15)*4;
    float4 v = make_float4(tile[c][t0], tile[c][t0+1], tile[c][t0+2], tile[c][t0+3]);
    *(float4*)(ob + (size_t)c*(N_*T_) + t0) = v;
  }
}

extern "C" void kernel_launch(void* const* d_in, const int* in_sizes, int n_in,
                              void* d_out, int out_size, void* d_ws, size_t ws_size,
                              hipStream_t stream){
  (void)in_sizes; (void)n_in; (void)out_size; (void)ws_size;
  const float* h   = (const float*)d_in[0];
  const int*   adj = (const int*)d_in[1];
  const float* W   = (const float*)d_in[2];
  const float* a   = (const float*)d_in[3];
  float* u    = (float*)d_ws;                       // 2*B*F f32
  float* fvec = u + 2*B_*F_;                        // B*N*T f32 (scaled, [b][n][t])
  float* gvec = fvec + B_*N_*T_;                    // B*N*T f32 (scaled, [b][n][t])
  unsigned short* wht = (unsigned short*)(gvec + B_*N_*T_);  // B*T*N*C bf16
  unsigned* amask = (unsigned*)(wht + (size_t)B_*T_*N_*C_);  // B*N*8 u32

  k_u   <<<dim3(B_),           dim3(F_),  0, stream>>>(W, a, u);
  k_whm <<<dim3(B_*N_ + B_*4), dim3(256), 0, stream>>>(h, W, u, adj, wht, fvec, gvec, amask);
  k_attn<<<dim3(B_*T_),        dim3(256), 0, stream>>>(wht, amask, fvec, gvec);
  k_tr  <<<dim3(B_*N_),        dim3(256), 0, stream>>>(wht, (float*)d_out);
}

// Round 14
// 102.217 us; speedup vs baseline: 1.2048x; 1.0320x over previous
//
#include <hip/hip_runtime.h>

#define B_ 16
#define F_ 128
#define N_ 256
#define T_ 64
#define C_ 64
#define ALPHA_ 0.2f
#define L2E_ 1.4426950408889634f

typedef short bf16x8 __attribute__((ext_vector_type(8)));
typedef float f32x4 __attribute__((ext_vector_type(4)));

__device__ __forceinline__ unsigned short f2bf(float x){
  unsigned int u = __float_as_uint(x);
  unsigned int r = u + 0x7FFFu + ((u >> 16) & 1u);   // RNE
  return (unsigned short)(r >> 16);
}
__device__ __forceinline__ unsigned pk2(float a, float b){
  return ((unsigned)f2bf(b) << 16) | (unsigned)f2bf(a);
}
// sign-extended single bit j of w: 0 -> 0x00000000, 1 -> 0xFFFFFFFF
__device__ __forceinline__ unsigned sbit(unsigned w, int j){
  return (unsigned)(((int)(w << (31 - j))) >> 31);
}
// LDS swizzle for Wh^T tile: varies with BOTH c&7 (read lanes) and c>>3 (write lanes)
__device__ __forceinline__ int swzT(int c){
  return ((c & 7) ^ ((c >> 3) & 7)) << 4;
}

// ---------------- Kernel A: u1[b][f] = sum_c W[b][f][c]*a1[b][c]; u2 with a2
__global__ void k_u(const float* __restrict__ W, const float* __restrict__ a,
                    float* __restrict__ u){
  int b = blockIdx.x, f = threadIdx.x;            // grid(B), block(F)
  const float* Wb = W + (b*F_ + f)*C_;
  const float* ab = a + b*2*C_;
  float s1 = 0.f, s2 = 0.f;
#pragma unroll 8
  for (int c = 0; c < C_; ++c){
    float w = Wb[c];
    s1 = fmaf(w, ab[c], s1);
    s2 = fmaf(w, ab[C_ + c], s2);
  }
  u[b*F_ + f] = s1;
  u[B_*F_ + b*F_ + f] = s2;
}

// ---------------- Kernel B (fused): blocks [0,B*N): Wh via MFMA + f/g;
// blocks [B*N, B*N + B*4): adjacency bitmask build (no data dep between halves)
__global__ __launch_bounds__(256, 4) void k_whm(const float* __restrict__ h,
    const float* __restrict__ W, const float* __restrict__ u,
    const int* __restrict__ adj,
    unsigned short* __restrict__ wht, float* __restrict__ fvec,
    float* __restrict__ gvec, unsigned* __restrict__ amask){
  __shared__ uint4 hT4[1024];    // 16KB: hT[t][f] bf16, 256B rows, XOR swz bits4-6
  __shared__ uint4 wT4[1024];    // 16KB: wT[c][f] bf16, same layout
  __shared__ float fpart[4][T_];
  __shared__ float gpart[4][T_];
  char* hT = (char*)hT4;
  char* wT = (char*)wT4;

  int bid = blockIdx.x;
  int tid = threadIdx.x, w = tid >> 6, l = tid & 63;

  if (bid >= B_*N_){
    // ---- mask half: adjacency row bitmasks, amask[b][n][8] u32
    int blk = bid - B_*N_;                // [0, B*4)
    int b = blk >> 2, r0 = (blk & 3)*64;
    const int* ab = adj + ((size_t)b*N_ + r0 + w*16)*N_;
    unsigned* om = amask + ((size_t)b*N_ + r0 + w*16)*8;
    for (int r = 0; r < 16; ++r){
      unsigned long long m0 = __ballot(ab[r*N_ +       l] > 0);
      unsigned long long m1 = __ballot(ab[r*N_ +  64 + l] > 0);
      unsigned long long m2 = __ballot(ab[r*N_ + 128 + l] > 0);
      unsigned long long m3 = __ballot(ab[r*N_ + 192 + l] > 0);
      if (l == 0){
        *(uint4*)(om + r*8)     = make_uint4((unsigned)m0, (unsigned)(m0>>32),
                                             (unsigned)m1, (unsigned)(m1>>32));
        *(uint4*)(om + r*8 + 4) = make_uint4((unsigned)m2, (unsigned)(m2>>32),
                                             (unsigned)m3, (unsigned)(m3>>32));
      }
    }
    return;
  }

  int b = bid >> 8, n = bid & 255;
  const float* hg = h + (size_t)b*F_*N_*T_ + n*T_;
  const float* Wg = W + b*F_*C_;
  const float* u1 = u + b*F_;
  const float* u2 = u + B_*F_ + b*F_;

  float sf = 0.f, sg = 0.f;
#pragma unroll
  for (int p = 0; p < 4; ++p){
    int f0 = p*32 + w*8;
    float v[8], wv[8];
#pragma unroll
    for (int j = 0; j < 8; ++j){
      v[j]  = hg[(size_t)(f0+j)*(N_*T_) + l];      // coalesced 256B per wave
      wv[j] = Wg[(f0+j)*C_ + l];                   // coalesced 256B per wave
      sf = fmaf(v[j], u1[f0+j], sf);               // f32 f/g (precision-critical)
      sg = fmaf(v[j], u2[f0+j], sg);
    }
    uint4 ph = make_uint4(pk2(v[0],v[1]),  pk2(v[2],v[3]),  pk2(v[4],v[5]),  pk2(v[6],v[7]));
    uint4 pw = make_uint4(pk2(wv[0],wv[1]),pk2(wv[2],wv[3]),pk2(wv[4],wv[5]),pk2(wv[6],wv[7]));
    *(uint4*)(hT + ((l*256 + f0*2) ^ ((l & 7) << 4))) = ph;   // hT[t=l][f0..f0+7]
    *(uint4*)(wT + ((l*256 + f0*2) ^ ((l & 7) << 4))) = pw;   // wT[c=l][f0..f0+7]
  }
  fpart[w][l] = sf;
  gpart[w][l] = sg;
  __syncthreads();

  if (tid < T_){
    float f_ = (fpart[0][tid] + fpart[1][tid]) + (fpart[2][tid] + fpart[3][tid]);
    float g_ = (gpart[0][tid] + gpart[1][tid]) + (gpart[2][tid] + gpart[3][tid]);
    fvec[(b*N_ + n)*T_ + tid] = f_ * L2E_;     // coalesced 256B
    gvec[(b*N_ + n)*T_ + tid] = g_ * L2E_;
  }

  // MFMA: D[c][t], wave w owns c rows [w*16, w*16+16)
  int li = l & 15, g_ = l >> 4;
  bf16x8 afr[4];
#pragma unroll
  for (int ch = 0; ch < 4; ++ch){
    int c = w*16 + li;
    afr[ch] = *(bf16x8*)(wT + ((c*256 + (ch*32 + g_*8)*2) ^ ((c & 7) << 4)));
  }
  f32x4 acc[4];
#pragma unroll
  for (int tt = 0; tt < 4; ++tt) acc[tt] = (f32x4){0.f,0.f,0.f,0.f};
#pragma unroll
  for (int tt = 0; tt < 4; ++tt){
#pragma unroll
    for (int ch = 0; ch < 4; ++ch){
      int t = tt*16 + li;
      bf16x8 bfr = *(bf16x8*)(hT + ((t*256 + (ch*32 + g_*8)*2) ^ ((t & 7) << 4)));
      acc[tt] = __builtin_amdgcn_mfma_f32_16x16x32_bf16(afr[ch], bfr, acc[tt], 0, 0, 0);
    }
  }

  // ---- LDS-bounce store (R13 win): scatter -> full-line writes
  __syncthreads();                       // all waves done reading hT/wT
  char* outT = hT;                       // reuse 8KB: outT[t][c] bf16, slot^=(t&7)
#pragma unroll
  for (int tt = 0; tt < 4; ++tt){
    int t = tt*16 + li;
    int c0 = w*16 + g_*4;
    unsigned q0 = pk2(acc[tt][0], acc[tt][1]);
    unsigned q1 = pk2(acc[tt][2], acc[tt][3]);
    *(uint2*)(outT + ((t*128 + c0*2) ^ ((t & 7) << 4))) = make_uint2(q0, q1);
  }
  __syncthreads();
  unsigned short* wb = wht + (size_t)b*T_*N_*C_ + n*C_;
#pragma unroll
  for (int k = 0; k < 2; ++k){
    int idx = tid + k*256;               // 512 16B chunks: 64 t x 8 c-slots
    int t = idx >> 3, c8 = idx & 7;
    uint4 vq = *(const uint4*)(outT + t*128 + ((c8 ^ (t & 7)) << 4));
    *(uint4*)(wb + (size_t)t*(N_*C_) + c8*8) = vq;   // full 128B line per t
  }
}

// ---------------- Kernel C: per (b,t,half-n), 256 threads, grid 2048 (8 blocks/CU
// queue -> staggered phases). Each block: 128 rows. T14 async-stage, masked-row-max
// softmax, MFMA PV, direct bf16 epilogue into wout (no in-place hazard)
__global__ __launch_bounds__(256, 4) void k_attn(
    const unsigned short* __restrict__ wht,   // [b][t][n][c] bf16
    unsigned short* __restrict__ wout,        // [b][t][n][c] bf16
    const unsigned* __restrict__ amask,       // [b][n][8]
    const float* __restrict__ fvec,           // [b][n][t], pre-scaled by log2e
    const float* __restrict__ gvec){          // [b][n][t], pre-scaled by log2e
  __shared__ uint4 whsT4[2048];   // 32KB: Wh^T [c][m] bf16, swzT-swizzled
  __shared__ float gs[N_];
  __shared__ float fs[128];
  __shared__ float invs[128];
  char* dstT = (char*)whsT4;

  int bid = blockIdx.x;
  int b = bid >> 7, t = (bid >> 1) & 63, nh = bid & 1;
  int nbase = nh*128;
  int tid = threadIdx.x, w = tid >> 6, l = tid & 63;
  int li = l & 15, g_ = l >> 4;

  // (1) g all rows; f for this half's 128 rows (stride-T reads, L2/L3-hot)
  gs[tid] = gvec[(b*N_ + tid)*T_ + t];
  if (tid < 128) fs[tid] = fvec[(b*N_ + nbase + tid)*T_ + t];

  // (2) masks (2 x uint4 per row) for lane's 2 rows -> packed pkl/pkh
  uint4 mlo[2], mhi[2];
#pragma unroll
  for (int mt = 0; mt < 2; ++mt){
    int n = nbase + w*32 + mt*16 + li;
    const uint4* mp = (const uint4*)(amask + ((size_t)b*N_ + n)*8);
    mlo[mt] = mp[0];
    mhi[mt] = mp[1];
  }
  unsigned pkl[2], pkh[2];
  unsigned selA = 0x0C0C0000u | ((unsigned)(g_ + 4) << 8) | (unsigned)g_;
#pragma unroll
  for (int mt = 0; mt < 2; ++mt){
    unsigned t0 = __builtin_amdgcn_perm(mlo[mt].y, mlo[mt].x, selA);
    unsigned t1 = __builtin_amdgcn_perm(mlo[mt].w, mlo[mt].z, selA);
    pkl[mt] = __builtin_amdgcn_perm(t1, t0, 0x05040100u);
    unsigned t2 = __builtin_amdgcn_perm(mhi[mt].y, mhi[mt].x, selA);
    unsigned t3 = __builtin_amdgcn_perm(mhi[mt].w, mhi[mt].z, selA);
    pkh[mt] = __builtin_amdgcn_perm(t3, t2, 0x05040100u);
  }

  // (3) ISSUE Wh staged loads (full slab; drain deferred past pass 1 — T14)
  const char* src = (const char*)(wht + (size_t)(b*T_ + t)*(N_*C_));
  uint4 ra[4], rb[4];
#pragma unroll
  for (int i = 0; i < 4; ++i){
    int q2 = tid + i*256;                  // 1024 2-row x 8-col tiles
    int m = (q2 >> 3)*2, c0 = (q2 & 7)*8;
    ra[i] = *(const uint4*)(src + m*128 + c0*2);
    rb[i] = *(const uint4*)(src + (m+1)*128 + c0*2);
  }

  // (4) barrier #1: LDS-only drain (raw s_barrier; staged loads stay in flight)
  asm volatile("s_waitcnt lgkmcnt(0)" ::: "memory");
  __builtin_amdgcn_sched_barrier(0);
  __builtin_amdgcn_s_barrier();

  float fl2[2];
#pragma unroll
  for (int mt = 0; mt < 2; ++mt) fl2[mt] = fs[w*32 + mt*16 + li];

  // (5) pass 1 (overlaps in-flight staged loads): masked per-row max of g.
  // Masked -> +0.0 (exact w.o.p.). TRUE masked max required (R5 NaN lesson).
  float mg[2] = {0.f, 0.f};
#pragma unroll 1
  for (int ch = 0; ch < 8; ++ch){
    const float* gq = &gs[ch*32 + g_*8];
    float4 ga = *(const float4*)gq;
    float4 gb = *(const float4*)(gq + 4);
    float gg[8] = {ga.x, ga.y, ga.z, ga.w, gb.x, gb.y, gb.z, gb.w};
    int sh = (ch & 3)*8;                    // wave-uniform -> SGPR
#pragma unroll
    for (int mt = 0; mt < 2; ++mt){
      unsigned wsh = ((ch & 4) ? pkh[mt] : pkl[mt]) >> sh;   // s_cselect + shift
      float cd[8];
#pragma unroll
      for (int j = 0; j < 8; ++j)
        cd[j] = __uint_as_float(__float_as_uint(gg[j]) & sbit(wsh, j));
      float m01 = fmaxf(cd[0], cd[1]), m23 = fmaxf(cd[2], cd[3]);
      float m45 = fmaxf(cd[4], cd[5]), m67 = fmaxf(cd[6], cd[7]);
      mg[mt] = fmaxf(mg[mt], fmaxf(fmaxf(m01, m23), fmaxf(m45, m67)));
    }
  }
  float fme[2], fme2[2];
#pragma unroll
  for (int mt = 0; mt < 2; ++mt){
    float v = mg[mt];
    v = fmaxf(v, __shfl_xor(v, 16));
    v = fmaxf(v, __shfl_xor(v, 32));
    float em = fl2[mt] + v;
    float M  = fmaxf(em, ALPHA_*em);     // exact masked row max of lrelu-logit (x L2E)
    fme[mt]  = fl2[mt] - M;
    fme2[mt] = fmaf(fl2[mt], ALPHA_, -M);
  }

  // (6) drain staged loads (counted vmcnt, compiler-inserted) -> perm -> LDS
#pragma unroll
  for (int i = 0; i < 4; ++i){
    int q2 = tid + i*256;
    int m = (q2 >> 3)*2, c0 = (q2 & 7)*8;
    unsigned va[4] = {ra[i].x, ra[i].y, ra[i].z, ra[i].w};
    unsigned vb[4] = {rb[i].x, rb[i].y, rb[i].z, rb[i].w};
#pragma unroll
    for (int k = 0; k < 4; ++k){
      int c = c0 + 2*k;
      unsigned lo = __builtin_amdgcn_perm(vb[k], va[k], 0x05040100u); // (m+1|m) @ col c
      unsigned hi = __builtin_amdgcn_perm(vb[k], va[k], 0x07060302u); // (m+1|m) @ col c+1
      *(unsigned*)(dstT + ((c*512 + m*2)     ^ swzT(c)))   = lo;
      *(unsigned*)(dstT + (((c+1)*512 + m*2) ^ swzT(c+1))) = hi;
    }
  }
  __syncthreads();

  // (7) pass 2: weights in A-frag layout -> MFMA PV (unroll 2)
  f32x4 acc[2][4];
#pragma unroll
  for (int mt = 0; mt < 2; ++mt)
#pragma unroll
    for (int nt = 0; nt < 4; ++nt)
      acc[mt][nt] = (f32x4){0.f, 0.f, 0.f, 0.f};
  float s0[2] = {0.f,0.f}, s1[2] = {0.f,0.f};

#pragma unroll 2
  for (int ch = 0; ch < 8; ++ch){
    bf16x8 bfr[4];
#pragma unroll
    for (int nt = 0; nt < 4; ++nt){
      int c = nt*16 + li;
      bfr[nt] = *(bf16x8*)(dstT + ((c*512 + (ch*32 + g_*8)*2) ^ swzT(c)));
    }
    const float* gq = &gs[ch*32 + g_*8];
    float4 ga = *(const float4*)gq;
    float4 gb = *(const float4*)(gq + 4);
    float gg[8] = {ga.x, ga.y, ga.z, ga.w, gb.x, gb.y, gb.z, gb.w};
    int sh = (ch & 3)*8;
#pragma unroll
    for (int mt = 0; mt < 2; ++mt){
      unsigned wsh = ((ch & 4) ? pkh[mt] : pkl[mt]) >> sh;
      float wv[8];
#pragma unroll
      for (int j = 0; j < 8; ++j){
        float d1 = gg[j] + fme[mt];                    // (lr - M)*L2E, branch 1
        float d2 = fmaf(gg[j], ALPHA_, fme2[mt]);      // branch 2
        float p  = exp2f(fmaxf(d1, d2));               // v_exp_f32
        float v  = __uint_as_float(__float_as_uint(p) & sbit(wsh, j));
        if (j < 4) s0[mt] += v; else s1[mt] += v;      // dual chains for ILP
        wv[j] = v;
      }
      unsigned q0, q1, q2_, q3;
      asm("v_cvt_pk_bf16_f32 %0, %1, %2" : "=v"(q0)  : "v"(wv[0]), "v"(wv[1]));
      asm("v_cvt_pk_bf16_f32 %0, %1, %2" : "=v"(q1)  : "v"(wv[2]), "v"(wv[3]));
      asm("v_cvt_pk_bf16_f32 %0, %1, %2" : "=v"(q2_) : "v"(wv[4]), "v"(wv[5]));
      asm("v_cvt_pk_bf16_f32 %0, %1, %2" : "=v"(q3)  : "v"(wv[6]), "v"(wv[7]));
      union { unsigned u[4]; bf16x8 v; } afu;
      afu.u[0] = q0; afu.u[1] = q1; afu.u[2] = q2_; afu.u[3] = q3;
#pragma unroll
      for (int nt = 0; nt < 4; ++nt)
        acc[mt][nt] = __builtin_amdgcn_mfma_f32_16x16x32_bf16(afu.v, bfr[nt], acc[mt][nt], 0, 0, 0);
    }
  }

  // ---- row sums -> invs (wave-local; same-wave ds_write/ds_read, no barrier)
#pragma unroll
  for (int mt = 0; mt < 2; ++mt){
    float s = s0[mt] + s1[mt];
    s += __shfl_xor(s, 16);
    s += __shfl_xor(s, 32);
    if (g_ == 0) invs[w*32 + mt*16 + li] = 1.0f / s;
  }

  // ---- epilogue: normalize + elu -> bf16 -> direct stores (same pattern as R13)
  unsigned short* ob = wout + (size_t)(b*T_ + t)*(N_*C_) + (size_t)nbase*C_;
#pragma unroll
  for (int mt = 0; mt < 2; ++mt){
#pragma unroll
    for (int reg = 0; reg < 4; ++reg){
      int rloc = w*32 + mt*16 + g_*4 + reg;     // D layout: row = g_*4+reg
      float inv = invs[rloc];
#pragma unroll
      for (int nt = 0; nt < 4; ++nt){
        float v = acc[mt][nt][reg] * inv;
        v = v > 0.f ? v : (__expf(v) - 1.f);    // elu
        ob[rloc*C_ + nt*16 + li] = f2bf(v);
      }
    }
  }
}

// ---------------- Kernel D: (b,t,n,c) bf16 -> (b,c,n,t) f32
__global__ __launch_bounds__(256) void k_tr(const unsigned short* __restrict__ whtO,
                                            float* __restrict__ out){
  __shared__ float tile[64][65];
  int bid = blockIdx.x;
  int b = bid >> 8, n = bid & 255;
  int tid = threadIdx.x;
  const unsigned short* src = whtO + ((size_t)b*T_*N_ + n)*C_;   // + t*N*C + c
#pragma unroll
  for (int i = 0; i < 2; ++i){
    int idx = tid + i*256;                 // 512 uint4 chunks: 64 t-rows x 8
    int t = idx >> 3, c0 = (idx & 7)*8;
    uint4 v = *(const uint4*)(src + (size_t)t*(N_*C_) + c0);
    unsigned arr[4] = {v.x, v.y, v.z, v.w};
#pragma unroll
    for (int k = 0; k < 4; ++k){
      tile[c0+2*k  ][t] = __uint_as_float(arr[k] << 16);
      tile[c0+2*k+1][t] = __uint_as_float(arr[k] & 0xFFFF0000u);
    }
  }
  __syncthreads();
  float* ob = out + (size_t)b*C_*N_*T_ + n*T_;                   // + c*N*T + t
#pragma unroll
  for (int i = 0; i < 4; ++i){
    int idx = tid + i*256;                 // 1024 float4: 64 c-rows x 16
    int c = idx >> 4, t0 = (idx & 15)*4;
    float4 v = make_float4(tile[c][t0], tile[c][t0+1], tile[c][t0+2], tile[c][t0+3]);
    *(float4*)(ob + (size_t)c*(N_*T_) + t0) = v;
  }
}

extern "C" void kernel_launch(void* const* d_in, const int* in_sizes, int n_in,
                              void* d_out, int out_size, void* d_ws, size_t ws_size,
                              hipStream_t stream){
  (void)in_sizes; (void)n_in; (void)out_size; (void)ws_size;
  const float* h   = (const float*)d_in[0];
  const int*   adj = (const int*)d_in[1];
  const float* W   = (const float*)d_in[2];
  const float* a   = (const float*)d_in[3];
  float* u    = (float*)d_ws;                       // 2*B*F f32
  float* fvec = u + 2*B_*F_;                        // B*N*T f32 (scaled, [b][n][t])
  float* gvec = fvec + B_*N_*T_;                    // B*N*T f32 (scaled, [b][n][t])
  unsigned short* wht = (unsigned short*)(gvec + B_*N_*T_);  // B*T*N*C bf16
  unsigned* amask = (unsigned*)(wht + (size_t)B_*T_*N_*C_);  // B*N*8 u32
  unsigned short* wout = (unsigned short*)(amask + (size_t)B_*N_*8); // B*T*N*C bf16

  k_u   <<<dim3(B_),           dim3(F_),  0, stream>>>(W, a, u);
  k_whm <<<dim3(B_*N_ + B_*4), dim3(256), 0, stream>>>(h, W, u, adj, wht, fvec, gvec, amask);
  k_attn<<<dim3(B_*T_*2),      dim3(256), 0, stream>>>(wht, wout, amask, fvec, gvec);
  k_tr  <<<dim3(B_*N_),        dim3(256), 0, stream>>>(wout, (float*)d_out);
}